// Round 4
// baseline (98.914 us; speedup 1.0000x reference)
//
#include <hip/hip_runtime.h>
#include <hip/hip_bf16.h>
#include <math.h>
#include <stdint.h>

// DotDecoder: out[e] = sigmoid(dot(c_feat[src[e]], g_feat[dst[e]])), D=64.
//
// R3: locality via on-device 2D bucketing.
//   Bucket b = g*16 + c, c = src/cdiv in [0,16), g = dst/gdiv in [0,8).
//   b % 8 == c % 8, so mapping process-blocks with blockIdx%8 == c%8 pins each
//   cell range to ONE XCD's L2 (cell fetch ~25.6MB once) while each XCD streams
//   its gene ranges (gene fetch ~8x5.1MB). Per-bucket working set ~2.2MB < 4MB L2.
//   Records are u64: e(20b) | src(17b) | dst(15b). Scatter uses per-block LDS
//   aggregation; overflow (>CAP, ~never) computed inline for correctness.

#define NCB 16
#define NGB 8
#define NB  (NCB * NGB)       // 128 buckets
#define CAP 12000u            // >> mean 7813 + 13 sigma
#define EPT 8                 // edges per thread in scatter

__device__ __forceinline__ float sigmoid_(float p) { return 1.0f / (1.0f + __expf(-p)); }

// ---------------- scatter: bucket edges into d_ws ----------------
__global__ __launch_bounds__(256) void scatter_kernel(
    const int* __restrict__ src_idx, const int* __restrict__ dst_idx,
    const float* __restrict__ c_feat, const float* __restrict__ g_feat,
    float* __restrict__ out,
    uint64_t* __restrict__ recs, uint32_t* __restrict__ cursor,
    int nE, int cdiv, int gdiv)
{
    __shared__ uint32_t lcount[NB];
    __shared__ uint32_t lbase[NB];
    const int tid = threadIdx.x;
    for (int i = tid; i < NB; i += 256) lcount[i] = 0;
    __syncthreads();

    const int base = blockIdx.x * (256 * EPT);
    bool     valid[EPT];
    uint32_t myb[EPT];
    uint32_t myrank[EPT];
    uint64_t mypack[EPT];

#pragma unroll
    for (int k = 0; k < EPT; k++) {
        const int e = base + tid + k * 256;
        valid[k] = (e < nE);
        if (valid[k]) {
            const int s = __builtin_nontemporal_load(src_idx + e);
            const int d = __builtin_nontemporal_load(dst_idx + e);
            uint32_t c = (uint32_t)s / (uint32_t)cdiv;  if (c >= NCB) c = NCB - 1;
            uint32_t g = (uint32_t)d / (uint32_t)gdiv;  if (g >= NGB) g = NGB - 1;
            const uint32_t b = g * NCB + c;
            myb[k]    = b;
            myrank[k] = atomicAdd(&lcount[b], 1u);
            mypack[k] = (uint64_t)(uint32_t)e | ((uint64_t)(uint32_t)s << 20) |
                        ((uint64_t)(uint32_t)d << 37);
        }
    }
    __syncthreads();
    for (int i = tid; i < NB; i += 256)
        lbase[i] = lcount[i] ? atomicAdd(&cursor[i], lcount[i]) : 0u;
    __syncthreads();

#pragma unroll
    for (int k = 0; k < EPT; k++) {
        if (!valid[k]) continue;
        const uint32_t b   = myb[k];
        const uint32_t pos = lbase[b] + myrank[k];
        if (pos < CAP) {
            __builtin_nontemporal_store(mypack[k], recs + (size_t)b * CAP + pos);
        } else {
            // overflow safety net (statistically never taken)
            const uint64_t v = mypack[k];
            const int e = (int)(v & 0xFFFFFu);
            const int s = (int)((v >> 20) & 0x1FFFFu);
            const int d = (int)((v >> 37) & 0x7FFFu);
            float p = 0.f;
            for (int j = 0; j < 64; j++)
                p += c_feat[(size_t)s * 64 + j] * g_feat[(size_t)d * 64 + j];
            out[e] = sigmoid_(p);
        }
    }
}

// ---------------- process: per-XCD bucket consumption ----------------
__global__ __launch_bounds__(256) void process_kernel(
    const float* __restrict__ c_feat, const float* __restrict__ g_feat,
    const uint64_t* __restrict__ recs, const uint32_t* __restrict__ cursor,
    float* __restrict__ out)
{
    // grid = 2048 blocks: x = XCD (bid%8), 16 bucket-slots per XCD, 16 blocks/bucket
    const int bid  = blockIdx.x;
    const int x    = bid & 7;
    const int t    = bid >> 3;        // 0..255
    const int slot = t >> 4;          // 0..15
    const int p    = t & 15;          // 0..15
    const int c    = x + 8 * (slot & 1);   // cell range: XCD x owns {x, x+8}
    const int g    = slot >> 1;            // gene range 0..7
    const int b    = g * NCB + c;

    uint32_t n = cursor[b];
    if (n > CAP) n = CAP;
    const uint32_t chunk = (n + 15u) >> 4;
    const uint32_t lo = (uint32_t)p * chunk;
    const uint32_t hi = (lo + chunk < n) ? (lo + chunk) : n;
    const uint64_t* rb = recs + (size_t)b * CAP;

    const int lane4 = threadIdx.x & 3;
    const int grp   = threadIdx.x >> 2;   // 0..63

    for (uint32_t r0 = lo + (uint32_t)grp * 2u; r0 < hi; r0 += 128u) {
        const uint64_t v0 = __builtin_nontemporal_load(rb + r0);
        const bool has2 = (r0 + 1u) < hi;
        const uint64_t v1 = has2 ? __builtin_nontemporal_load(rb + r0 + 1) : v0;

        const int e0 = (int)(v0 & 0xFFFFFu);
        const int s0 = (int)((v0 >> 20) & 0x1FFFFu);
        const int d0 = (int)((v0 >> 37) & 0x7FFFu);
        const int e1 = (int)(v1 & 0xFFFFFu);
        const int s1 = (int)((v1 >> 20) & 0x1FFFFu);
        const int d1 = (int)((v1 >> 37) & 0x7FFFu);

        const float4* a0p = reinterpret_cast<const float4*>(c_feat + (size_t)s0 * 64) + lane4;
        const float4* b0p = reinterpret_cast<const float4*>(g_feat + (size_t)d0 * 64) + lane4;
        const float4* a1p = reinterpret_cast<const float4*>(c_feat + (size_t)s1 * 64) + lane4;
        const float4* b1p = reinterpret_cast<const float4*>(g_feat + (size_t)d1 * 64) + lane4;

        const float4 a00 = a0p[0];
        const float4 a01 = a0p[4];
        const float4 a02 = a0p[8];
        const float4 a03 = a0p[12];
        const float4 b00 = b0p[0];
        const float4 b01 = b0p[4];
        const float4 b02 = b0p[8];
        const float4 b03 = b0p[12];
        const float4 a10 = a1p[0];
        const float4 a11 = a1p[4];
        const float4 a12 = a1p[8];
        const float4 a13 = a1p[12];
        const float4 b10 = b1p[0];
        const float4 b11 = b1p[4];
        const float4 b12 = b1p[8];
        const float4 b13 = b1p[12];

        float p0 = a00.x * b00.x + a00.y * b00.y + a00.z * b00.z + a00.w * b00.w;
        p0 += a01.x * b01.x + a01.y * b01.y + a01.z * b01.z + a01.w * b01.w;
        p0 += a02.x * b02.x + a02.y * b02.y + a02.z * b02.z + a02.w * b02.w;
        p0 += a03.x * b03.x + a03.y * b03.y + a03.z * b03.z + a03.w * b03.w;

        float p1 = a10.x * b10.x + a10.y * b10.y + a10.z * b10.z + a10.w * b10.w;
        p1 += a11.x * b11.x + a11.y * b11.y + a11.z * b11.z + a11.w * b11.w;
        p1 += a12.x * b12.x + a12.y * b12.y + a12.z * b12.z + a12.w * b12.w;
        p1 += a13.x * b13.x + a13.y * b13.y + a13.z * b13.z + a13.w * b13.w;

        p0 += __shfl_xor(p0, 1, 4);
        p0 += __shfl_xor(p0, 2, 4);
        p1 += __shfl_xor(p1, 1, 4);
        p1 += __shfl_xor(p1, 2, 4);

        if (lane4 == 0) {
            __builtin_nontemporal_store(sigmoid_(p0), out + e0);
            if (has2) __builtin_nontemporal_store(sigmoid_(p1), out + e1);
        }
    }
}

// ---------------- fallback (R2 kernel) ----------------
__global__ __launch_bounds__(256) void dot_decoder_fallback(
    const float* __restrict__ c_feat, const float* __restrict__ g_feat,
    const int* __restrict__ src_idx, const int* __restrict__ dst_idx,
    float* __restrict__ out, int nE)
{
    const int lane4 = threadIdx.x & 3;
    const int g = (int)((blockIdx.x * (unsigned)blockDim.x + threadIdx.x) >> 2);
    const int e0 = g * 2;
    if (e0 >= nE) return;
    const bool has2 = (e0 + 1) < nE;
    const int e1 = has2 ? (e0 + 1) : e0;

    const int s0 = src_idx[e0], d0 = dst_idx[e0];
    const int s1 = src_idx[e1], d1 = dst_idx[e1];

    const float4* a0p = reinterpret_cast<const float4*>(c_feat + (size_t)s0 * 64) + lane4;
    const float4* b0p = reinterpret_cast<const float4*>(g_feat + (size_t)d0 * 64) + lane4;
    const float4* a1p = reinterpret_cast<const float4*>(c_feat + (size_t)s1 * 64) + lane4;
    const float4* b1p = reinterpret_cast<const float4*>(g_feat + (size_t)d1 * 64) + lane4;

    float p0 = 0.f, p1 = 0.f;
#pragma unroll
    for (int k = 0; k < 4; k++) {
        const float4 a = a0p[4 * k], b = b0p[4 * k];
        p0 += a.x * b.x + a.y * b.y + a.z * b.z + a.w * b.w;
    }
#pragma unroll
    for (int k = 0; k < 4; k++) {
        const float4 a = a1p[4 * k], b = b1p[4 * k];
        p1 += a.x * b.x + a.y * b.y + a.z * b.z + a.w * b.w;
    }
    p0 += __shfl_xor(p0, 1, 4);
    p0 += __shfl_xor(p0, 2, 4);
    p1 += __shfl_xor(p1, 1, 4);
    p1 += __shfl_xor(p1, 2, 4);
    if (lane4 == 0) {
        out[e0] = sigmoid_(p0);
        if (has2) out[e1] = sigmoid_(p1);
    }
}

extern "C" void kernel_launch(void* const* d_in, const int* in_sizes, int n_in,
                              void* d_out, int out_size, void* d_ws, size_t ws_size,
                              hipStream_t stream) {
    const float* c_feat = (const float*)d_in[0];
    const float* g_feat = (const float*)d_in[1];
    const int*   src    = (const int*)d_in[2];
    const int*   dst    = (const int*)d_in[3];
    float* out = (float*)d_out;

    const int nE      = in_sizes[2];
    const int n_cells = in_sizes[0] / 64;
    const int n_genes = in_sizes[1] / 64;

    // ws layout: [cursor: NB u32][recs: NB*CAP u64]
    const size_t cursor_bytes = NB * sizeof(uint32_t);
    const size_t recs_off     = 512;  // aligned
    const size_t needed       = recs_off + (size_t)NB * CAP * sizeof(uint64_t);

    const bool can_bucket = (nE <= (1 << 20)) && (n_cells <= (1 << 17)) &&
                            (n_genes <= (1 << 15)) && (ws_size >= needed);

    if (!can_bucket) {
        const int threads = 256;
        const int epb = (threads / 4) * 2;
        const int blocks = (nE + epb - 1) / epb;
        dot_decoder_fallback<<<blocks, threads, 0, stream>>>(c_feat, g_feat, src, dst, out, nE);
        return;
    }

    uint32_t* cursor = (uint32_t*)d_ws;
    uint64_t* recs   = (uint64_t*)((char*)d_ws + recs_off);

    const int cdiv = (n_cells + NCB - 1) / NCB;   // 6250
    const int gdiv = (n_genes + NGB - 1) / NGB;   // 2500

    hipMemsetAsync(cursor, 0, cursor_bytes, stream);

    const int sc_blocks = (nE + 256 * EPT - 1) / (256 * EPT);
    scatter_kernel<<<sc_blocks, 256, 0, stream>>>(src, dst, c_feat, g_feat, out,
                                                  recs, cursor, nE, cdiv, gdiv);

    process_kernel<<<2048, 256, 0, stream>>>(c_feat, g_feat, recs, cursor, out);
}

// Round 6
// 40.834 us; speedup vs baseline: 2.4223x; 2.4223x over previous
//
#include <hip/hip_runtime.h>
#include <hip/hip_bf16.h>
#include <hip/hip_fp16.h>
#include <math.h>
#include <stdint.h>

// DotDecoder: out[e] = sigmoid(dot(c_feat[src[e]], g_feat[dst[e]])), D=64.
//
// R5 (= R4 with compile fix): time is bound by gather TRANSACTION COUNT
// (per-CU scattered 64B transaction rate; invariant to L2 hit rate per R3).
// Halve transactions: convert tables to fp16 in d_ws (rows 256B -> 128B,
// 8 -> 4 transactions/edge). fp16 storage error -> <=~0.004 on sigmoid output.

__device__ __forceinline__ float sigmoid_(float p) { return 1.0f / (1.0f + __expf(-p)); }

// ---------- convert f32 -> f16 (vectorized, streaming) ----------
__global__ __launch_bounds__(256) void convert_kernel(
    const float* __restrict__ in, __half* __restrict__ outp, int n4)
{
    int i = blockIdx.x * 256 + threadIdx.x;
    const int stride = gridDim.x * 256;
    for (; i < n4; i += stride) {
        const float4 v = reinterpret_cast<const float4*>(in)[i];
        __half2 h0 = __float22half2_rn(make_float2(v.x, v.y));
        __half2 h1 = __float22half2_rn(make_float2(v.z, v.w));
        uint2 pk;
        pk.x = *reinterpret_cast<uint32_t*>(&h0);
        pk.y = *reinterpret_cast<uint32_t*>(&h1);
        *reinterpret_cast<uint2*>(outp + (size_t)i * 4) = pk;
    }
}

// ---------- fp16 dot helper: 8 halves x 8 halves -> f32 ----------
__device__ __forceinline__ float dot8h(uint4 a, uint4 b) {
    const __half2* pa = reinterpret_cast<const __half2*>(&a);
    const __half2* pb = reinterpret_cast<const __half2*>(&b);
    float s = 0.f;
#pragma unroll
    for (int i = 0; i < 4; i++) {
        const float2 fa = __half22float2(pa[i]);
        const float2 fb = __half22float2(pb[i]);
        s += fa.x * fb.x + fa.y * fb.y;
    }
    return s;
}

// ---------- gather: both tables fp16 ----------
__global__ __launch_bounds__(256) void gather_hh(
    const __half* __restrict__ ch, const __half* __restrict__ gh,
    const int* __restrict__ src_idx, const int* __restrict__ dst_idx,
    float* __restrict__ out, int nE)
{
    const int lane4 = threadIdx.x & 3;
    const int g = (int)((blockIdx.x * 256u + threadIdx.x) >> 2);
    const int e0 = g * 2;
    if (e0 >= nE) return;
    const bool has2 = (e0 + 1) < nE;
    const int e1 = has2 ? (e0 + 1) : e0;

    const int s0 = __builtin_nontemporal_load(src_idx + e0);
    const int d0 = __builtin_nontemporal_load(dst_idx + e0);
    const int s1 = __builtin_nontemporal_load(src_idx + e1);
    const int d1 = __builtin_nontemporal_load(dst_idx + e1);

    // row = 64 halves = 128B = 8x uint4; lane4 covers 16B at lane4, then +64B
    const uint4* a0p = reinterpret_cast<const uint4*>(ch + (size_t)s0 * 64) + lane4;
    const uint4* b0p = reinterpret_cast<const uint4*>(gh + (size_t)d0 * 64) + lane4;
    const uint4* a1p = reinterpret_cast<const uint4*>(ch + (size_t)s1 * 64) + lane4;
    const uint4* b1p = reinterpret_cast<const uint4*>(gh + (size_t)d1 * 64) + lane4;

    const uint4 a0l = a0p[0];
    const uint4 a0h = a0p[4];
    const uint4 b0l = b0p[0];
    const uint4 b0h = b0p[4];
    const uint4 a1l = a1p[0];
    const uint4 a1h = a1p[4];
    const uint4 b1l = b1p[0];
    const uint4 b1h = b1p[4];

    float p0 = dot8h(a0l, b0l) + dot8h(a0h, b0h);
    float p1 = dot8h(a1l, b1l) + dot8h(a1h, b1h);

    p0 += __shfl_xor(p0, 1, 4);
    p0 += __shfl_xor(p0, 2, 4);
    p1 += __shfl_xor(p1, 1, 4);
    p1 += __shfl_xor(p1, 2, 4);

    if (lane4 == 0) {
        __builtin_nontemporal_store(sigmoid_(p0), out + e0);
        if (has2) __builtin_nontemporal_store(sigmoid_(p1), out + e1);
    }
}

// ---------- gather: c fp16, g f32 (ws too small for both tables) ----------
__global__ __launch_bounds__(256) void gather_hf(
    const __half* __restrict__ ch, const float* __restrict__ g_feat,
    const int* __restrict__ src_idx, const int* __restrict__ dst_idx,
    float* __restrict__ out, int nE)
{
    const int lane4 = threadIdx.x & 3;
    const int g = (int)((blockIdx.x * 256u + threadIdx.x) >> 2);
    const int e = (int)g;
    if (e >= nE) return;

    const int s = __builtin_nontemporal_load(src_idx + e);
    const int d = __builtin_nontemporal_load(dst_idx + e);

    // a: halves, lane owns elems [lane4*8..+8) and [32+lane4*8..+8)
    const uint4* ap = reinterpret_cast<const uint4*>(ch + (size_t)s * 64);
    const uint4 aLo = ap[lane4 * 2];        // elems lane4*8 .. +8  (16B granule x2)
    const uint4 aHi = ap[lane4 * 2 + 1];    // wait: lane4*2 covers 8 halves? u4=8 halves
    // NOTE: uint4 = 16B = 8 halves, so ap[lane4] = elems [lane4*8..+8).
    // Use contiguous ownership: lane owns [lane4*16 .. +16) elems = 2 uint4.
    const uint4 a0 = ap[lane4 * 2];
    const uint4 a1 = ap[lane4 * 2 + 1];
    (void)aLo; (void)aHi;

    // b: floats at the same element offsets: [lane4*16..+16) = 4 float4
    const float4* bp = reinterpret_cast<const float4*>(g_feat + (size_t)d * 64) + lane4 * 4;
    const float4 b0 = bp[0];
    const float4 b1 = bp[1];
    const float4 b2 = bp[2];
    const float4 b3 = bp[3];

    float af[16];
    {
        const __half2* p0h = reinterpret_cast<const __half2*>(&a0);
        const __half2* p1h = reinterpret_cast<const __half2*>(&a1);
#pragma unroll
        for (int i = 0; i < 4; i++) {
            float2 f = __half22float2(p0h[i]);
            af[2 * i] = f.x; af[2 * i + 1] = f.y;
        }
#pragma unroll
        for (int i = 0; i < 4; i++) {
            float2 f = __half22float2(p1h[i]);
            af[8 + 2 * i] = f.x; af[8 + 2 * i + 1] = f.y;
        }
    }

    float p = af[0] * b0.x + af[1] * b0.y + af[2] * b0.z + af[3] * b0.w
            + af[4] * b1.x + af[5] * b1.y + af[6] * b1.z + af[7] * b1.w
            + af[8] * b2.x + af[9] * b2.y + af[10] * b2.z + af[11] * b2.w
            + af[12] * b3.x + af[13] * b3.y + af[14] * b3.z + af[15] * b3.w;

    p += __shfl_xor(p, 1, 4);
    p += __shfl_xor(p, 2, 4);

    if (lane4 == 0) {
        __builtin_nontemporal_store(sigmoid_(p), out + e);
    }
}

// ---------- fallback: pure f32 (R2 kernel) ----------
__global__ __launch_bounds__(256) void gather_ff(
    const float* __restrict__ c_feat, const float* __restrict__ g_feat,
    const int* __restrict__ src_idx, const int* __restrict__ dst_idx,
    float* __restrict__ out, int nE)
{
    const int lane4 = threadIdx.x & 3;
    const int g = (int)((blockIdx.x * 256u + threadIdx.x) >> 2);
    const int e0 = g * 2;
    if (e0 >= nE) return;
    const bool has2 = (e0 + 1) < nE;
    const int e1 = has2 ? (e0 + 1) : e0;

    const int s0 = src_idx[e0], d0 = dst_idx[e0];
    const int s1 = src_idx[e1], d1 = dst_idx[e1];

    const float4* a0p = reinterpret_cast<const float4*>(c_feat + (size_t)s0 * 64) + lane4;
    const float4* b0p = reinterpret_cast<const float4*>(g_feat + (size_t)d0 * 64) + lane4;
    const float4* a1p = reinterpret_cast<const float4*>(c_feat + (size_t)s1 * 64) + lane4;
    const float4* b1p = reinterpret_cast<const float4*>(g_feat + (size_t)d1 * 64) + lane4;

    float p0 = 0.f, p1 = 0.f;
#pragma unroll
    for (int k = 0; k < 4; k++) {
        const float4 a = a0p[4 * k], b = b0p[4 * k];
        p0 += a.x * b.x + a.y * b.y + a.z * b.z + a.w * b.w;
    }
#pragma unroll
    for (int k = 0; k < 4; k++) {
        const float4 a = a1p[4 * k], b = b1p[4 * k];
        p1 += a.x * b.x + a.y * b.y + a.z * b.z + a.w * b.w;
    }
    p0 += __shfl_xor(p0, 1, 4);
    p0 += __shfl_xor(p0, 2, 4);
    p1 += __shfl_xor(p1, 1, 4);
    p1 += __shfl_xor(p1, 2, 4);
    if (lane4 == 0) {
        out[e0] = sigmoid_(p0);
        if (has2) out[e1] = sigmoid_(p1);
    }
}

extern "C" void kernel_launch(void* const* d_in, const int* in_sizes, int n_in,
                              void* d_out, int out_size, void* d_ws, size_t ws_size,
                              hipStream_t stream) {
    const float* c_feat = (const float*)d_in[0];
    const float* g_feat = (const float*)d_in[1];
    const int*   src    = (const int*)d_in[2];
    const int*   dst    = (const int*)d_in[3];
    float* out = (float*)d_out;

    const int nE  = in_sizes[2];
    const int nc4 = in_sizes[0] / 4;   // c_feat float4 count
    const int ng4 = in_sizes[1] / 4;   // g_feat float4 count

    const size_t c_bytes = (size_t)in_sizes[0] * sizeof(__half);  // 12.8 MB
    const size_t g_bytes = (size_t)in_sizes[1] * sizeof(__half);  // 2.56 MB
    const size_t g_off   = (c_bytes + 255) & ~(size_t)255;

    const int threads = 256;

    if (ws_size >= g_off + g_bytes) {
        __half* ch = (__half*)d_ws;
        __half* gh = (__half*)((char*)d_ws + g_off);
        convert_kernel<<<(nc4 + 255) / 256, 256, 0, stream>>>(c_feat, ch, nc4);
        convert_kernel<<<(ng4 + 255) / 256, 256, 0, stream>>>(g_feat, gh, ng4);
        const int epb = (threads / 4) * 2;  // 128 edges / block
        const int gblocks = (nE + epb - 1) / epb;
        gather_hh<<<gblocks, threads, 0, stream>>>(ch, gh, src, dst, out, nE);
    } else if (ws_size >= c_bytes) {
        __half* ch = (__half*)d_ws;
        convert_kernel<<<(nc4 + 255) / 256, 256, 0, stream>>>(c_feat, ch, nc4);
        const int epb = threads / 4;        // 64 edges / block
        const int gblocks = (nE + epb - 1) / epb;
        gather_hf<<<gblocks, threads, 0, stream>>>(ch, g_feat, src, dst, out, nE);
    } else {
        const int epb = (threads / 4) * 2;
        const int gblocks = (nE + epb - 1) / epb;
        gather_ff<<<gblocks, threads, 0, stream>>>(c_feat, g_feat, src, dst, out, nE);
    }
}

// Round 7
// 38.509 us; speedup vs baseline: 2.5686x; 1.0604x over previous
//
#include <hip/hip_runtime.h>
#include <hip/hip_bf16.h>
#include <hip/hip_fp16.h>
#include <math.h>
#include <stdint.h>

// DotDecoder: out[e] = sigmoid(dot(c_feat[src[e]], g_feat[dst[e]])), D=64.
//
// R6: established model — time = scattered-segment rate (~7us per M 64B
// segments, CU-side) + streaming BW. fp16 tables give 4 segs/edge (confirmed
// ~30us gather). This round: merge the two convert kernels into one launch
// to shave serial launch/tail overhead (~2-3us).

__device__ __forceinline__ float sigmoid_(float p) { return 1.0f / (1.0f + __expf(-p)); }

// ---------- convert BOTH tables f32 -> f16 in one launch ----------
__global__ __launch_bounds__(256) void convert_both(
    const float* __restrict__ c_feat, const float* __restrict__ g_feat,
    __half* __restrict__ ch, __half* __restrict__ gh, int nc4, int ng4)
{
    const int total = nc4 + ng4;
    int i = blockIdx.x * 256 + threadIdx.x;
    const int stride = gridDim.x * 256;
    for (; i < total; i += stride) {
        const float* inp;
        __half* outp;
        int j;
        if (i < nc4) { inp = c_feat; outp = ch; j = i; }
        else         { inp = g_feat; outp = gh; j = i - nc4; }
        const float4 v = reinterpret_cast<const float4*>(inp)[j];
        __half2 h0 = __float22half2_rn(make_float2(v.x, v.y));
        __half2 h1 = __float22half2_rn(make_float2(v.z, v.w));
        uint2 pk;
        pk.x = *reinterpret_cast<uint32_t*>(&h0);
        pk.y = *reinterpret_cast<uint32_t*>(&h1);
        *reinterpret_cast<uint2*>(outp + (size_t)j * 4) = pk;
    }
}

// ---------- fp16 dot helper: 8 halves x 8 halves -> f32 ----------
__device__ __forceinline__ float dot8h(uint4 a, uint4 b) {
    const __half2* pa = reinterpret_cast<const __half2*>(&a);
    const __half2* pb = reinterpret_cast<const __half2*>(&b);
    float s = 0.f;
#pragma unroll
    for (int i = 0; i < 4; i++) {
        const float2 fa = __half22float2(pa[i]);
        const float2 fb = __half22float2(pb[i]);
        s += fa.x * fb.x + fa.y * fb.y;
    }
    return s;
}

// ---------- gather: both tables fp16 ----------
__global__ __launch_bounds__(256) void gather_hh(
    const __half* __restrict__ ch, const __half* __restrict__ gh,
    const int* __restrict__ src_idx, const int* __restrict__ dst_idx,
    float* __restrict__ out, int nE)
{
    const int lane4 = threadIdx.x & 3;
    const int g = (int)((blockIdx.x * 256u + threadIdx.x) >> 2);
    const int e0 = g * 2;
    if (e0 >= nE) return;
    const bool has2 = (e0 + 1) < nE;
    const int e1 = has2 ? (e0 + 1) : e0;

    const int s0 = __builtin_nontemporal_load(src_idx + e0);
    const int d0 = __builtin_nontemporal_load(dst_idx + e0);
    const int s1 = __builtin_nontemporal_load(src_idx + e1);
    const int d1 = __builtin_nontemporal_load(dst_idx + e1);

    // row = 64 halves = 128B = 8x uint4; lane4 covers 16B at lane4, then +64B
    const uint4* a0p = reinterpret_cast<const uint4*>(ch + (size_t)s0 * 64) + lane4;
    const uint4* b0p = reinterpret_cast<const uint4*>(gh + (size_t)d0 * 64) + lane4;
    const uint4* a1p = reinterpret_cast<const uint4*>(ch + (size_t)s1 * 64) + lane4;
    const uint4* b1p = reinterpret_cast<const uint4*>(gh + (size_t)d1 * 64) + lane4;

    const uint4 a0l = a0p[0];
    const uint4 a0h = a0p[4];
    const uint4 b0l = b0p[0];
    const uint4 b0h = b0p[4];
    const uint4 a1l = a1p[0];
    const uint4 a1h = a1p[4];
    const uint4 b1l = b1p[0];
    const uint4 b1h = b1p[4];

    float p0 = dot8h(a0l, b0l) + dot8h(a0h, b0h);
    float p1 = dot8h(a1l, b1l) + dot8h(a1h, b1h);

    p0 += __shfl_xor(p0, 1, 4);
    p0 += __shfl_xor(p0, 2, 4);
    p1 += __shfl_xor(p1, 1, 4);
    p1 += __shfl_xor(p1, 2, 4);

    if (lane4 == 0) {
        __builtin_nontemporal_store(sigmoid_(p0), out + e0);
        if (has2) __builtin_nontemporal_store(sigmoid_(p1), out + e1);
    }
}

// ---------- fallback: pure f32 (R2 kernel) ----------
__global__ __launch_bounds__(256) void gather_ff(
    const float* __restrict__ c_feat, const float* __restrict__ g_feat,
    const int* __restrict__ src_idx, const int* __restrict__ dst_idx,
    float* __restrict__ out, int nE)
{
    const int lane4 = threadIdx.x & 3;
    const int g = (int)((blockIdx.x * 256u + threadIdx.x) >> 2);
    const int e0 = g * 2;
    if (e0 >= nE) return;
    const bool has2 = (e0 + 1) < nE;
    const int e1 = has2 ? (e0 + 1) : e0;

    const int s0 = src_idx[e0], d0 = dst_idx[e0];
    const int s1 = src_idx[e1], d1 = dst_idx[e1];

    const float4* a0p = reinterpret_cast<const float4*>(c_feat + (size_t)s0 * 64) + lane4;
    const float4* b0p = reinterpret_cast<const float4*>(g_feat + (size_t)d0 * 64) + lane4;
    const float4* a1p = reinterpret_cast<const float4*>(c_feat + (size_t)s1 * 64) + lane4;
    const float4* b1p = reinterpret_cast<const float4*>(g_feat + (size_t)d1 * 64) + lane4;

    float p0 = 0.f, p1 = 0.f;
#pragma unroll
    for (int k = 0; k < 4; k++) {
        const float4 a = a0p[4 * k], b = b0p[4 * k];
        p0 += a.x * b.x + a.y * b.y + a.z * b.z + a.w * b.w;
    }
#pragma unroll
    for (int k = 0; k < 4; k++) {
        const float4 a = a1p[4 * k], b = b1p[4 * k];
        p1 += a.x * b.x + a.y * b.y + a.z * b.z + a.w * b.w;
    }
    p0 += __shfl_xor(p0, 1, 4);
    p0 += __shfl_xor(p0, 2, 4);
    p1 += __shfl_xor(p1, 1, 4);
    p1 += __shfl_xor(p1, 2, 4);
    if (lane4 == 0) {
        out[e0] = sigmoid_(p0);
        if (has2) out[e1] = sigmoid_(p1);
    }
}

extern "C" void kernel_launch(void* const* d_in, const int* in_sizes, int n_in,
                              void* d_out, int out_size, void* d_ws, size_t ws_size,
                              hipStream_t stream) {
    const float* c_feat = (const float*)d_in[0];
    const float* g_feat = (const float*)d_in[1];
    const int*   src    = (const int*)d_in[2];
    const int*   dst    = (const int*)d_in[3];
    float* out = (float*)d_out;

    const int nE  = in_sizes[2];
    const int nc4 = in_sizes[0] / 4;   // c_feat float4 count
    const int ng4 = in_sizes[1] / 4;   // g_feat float4 count

    const size_t c_bytes = (size_t)in_sizes[0] * sizeof(__half);  // 12.8 MB
    const size_t g_bytes = (size_t)in_sizes[1] * sizeof(__half);  // 2.56 MB
    const size_t g_off   = (c_bytes + 255) & ~(size_t)255;

    const int threads = 256;
    const int epb = (threads / 4) * 2;  // 128 edges / block
    const int gblocks = (nE + epb - 1) / epb;

    if (ws_size >= g_off + g_bytes) {
        __half* ch = (__half*)d_ws;
        __half* gh = (__half*)((char*)d_ws + g_off);
        const int total4 = nc4 + ng4;
        int cblocks = (total4 + 255) / 256;
        if (cblocks > 2048) cblocks = 2048;   // grid-stride handles the rest
        convert_both<<<cblocks, 256, 0, stream>>>(c_feat, g_feat, ch, gh, nc4, ng4);
        gather_hh<<<gblocks, threads, 0, stream>>>(ch, gh, src, dst, out, nE);
    } else {
        gather_ff<<<gblocks, threads, 0, stream>>>(c_feat, g_feat, src, dst, out, nE);
    }
}